// Round 8
// baseline (351.273 us; speedup 1.0000x reference)
//
#include <hip/hip_runtime.h>
#include <hip/hip_bf16.h>
#include <math.h>

#define Bc 32
#define Cc 64
#define Sc 128
#define Zc 64
#define Dc 256
#define VOc 5000

typedef __attribute__((ext_vector_type(8))) short v8s;   // 8 bf16 = 4 VGPR MFMA frag
typedef __attribute__((ext_vector_type(4))) float f4;    // 16x16 accum

union FQ { uint4 q; v8s s; };
struct HL { v8s hi, lo; };

__device__ __forceinline__ unsigned short bf_bits(__hip_bfloat16 h) {
  union { __hip_bfloat16 b; unsigned short u; } cv; cv.b = h; return cv.u;
}

__device__ __forceinline__ void split_hl(float x, unsigned short& h, unsigned short& l) {
  __hip_bfloat16 hh = __float2bfloat16(x);
  float hf = __bfloat162float(hh);
  __hip_bfloat16 ll = __float2bfloat16(x - hf);
  h = bf_bits(hh); l = bf_bits(ll);
}

__device__ __forceinline__ unsigned pack_hl(float x) {
  unsigned short h, l; split_hl(x, h, l);
  return (unsigned)h | ((unsigned)l << 16);
}

__device__ __forceinline__ HL unpack8(uint4 q0, uint4 q1) {
  FQ h, l;
  h.q.x = __builtin_amdgcn_perm(q0.y, q0.x, 0x05040100u);
  h.q.y = __builtin_amdgcn_perm(q0.w, q0.z, 0x05040100u);
  h.q.z = __builtin_amdgcn_perm(q1.y, q1.x, 0x05040100u);
  h.q.w = __builtin_amdgcn_perm(q1.w, q1.z, 0x05040100u);
  l.q.x = __builtin_amdgcn_perm(q0.y, q0.x, 0x07060302u);
  l.q.y = __builtin_amdgcn_perm(q0.w, q0.z, 0x07060302u);
  l.q.z = __builtin_amdgcn_perm(q1.y, q1.x, 0x07060302u);
  l.q.w = __builtin_amdgcn_perm(q1.w, q1.z, 0x07060302u);
  HL r; r.hi = h.s; r.lo = l.s; return r;
}

__device__ __forceinline__ f4 mm3p(v8s ah, v8s al, v8s bh, v8s bl, f4 c) {
  c = __builtin_amdgcn_mfma_f32_16x16x32_bf16(ah, bh, c, 0, 0, 0);
  c = __builtin_amdgcn_mfma_f32_16x16x32_bf16(ah, bl, c, 0, 0, 0);
  c = __builtin_amdgcn_mfma_f32_16x16x32_bf16(al, bh, c, 0, 0, 0);
  return c;
}
__device__ __forceinline__ f4 mm3h(const HL& A, v8s bh, v8s bl, f4 c) {
  return mm3p(A.hi, A.lo, bh, bl, c);
}

// ---------------------------------------------------------------------------
// prep: WT[j][k] = Wseg[k][n] transposed + hi/lo split. j = seg*256+n.
// ---------------------------------------------------------------------------
__global__ __launch_bounds__(256) void prep_kernel(
    const float* __restrict__ FW, const float* __restrict__ GW,
    unsigned short* __restrict__ WT_hi, unsigned short* __restrict__ WT_lo)
{
  const int j = blockIdx.x, t = threadIdx.x;
  const int seg = j >> 8, n = j & 255;
  float v;
  if (seg == 0) v = FW[(size_t)t * 256 + n];
  else if (seg == 1) v = GW[(size_t)t * 256 + n];
  else v = GW[(size_t)(256 + t) * 256 + n];
  unsigned short h, l; split_hl(v, h, l);
  WT_hi[(size_t)j * 256 + t] = h;
  WT_lo[(size_t)j * 256 + t] = l;
}

// ---------------------------------------------------------------------------
// Transform (MFMA 3-term, software-pipelined staging, LDS-coalesced epilogue).
// 64 rows x 128 cols per block; K=256 in 8 chunks of 32.
// ---------------------------------------------------------------------------
__global__ __launch_bounds__(256, 4) void transform_kernel(
    const float* __restrict__ EmbA, const int* __restrict__ inp,
    const float* __restrict__ EmbB,
    const unsigned short* __restrict__ WT_hi, const unsigned short* __restrict__ WT_lo,
    const float* __restrict__ Fb, const float* __restrict__ Gb,
    unsigned short* __restrict__ Am_hi, unsigned short* __restrict__ Am_lo,
    float* __restrict__ Ta,
    unsigned short* __restrict__ UaT_hi, unsigned short* __restrict__ UaT_lo,
    unsigned short* __restrict__ FB_hi, unsigned short* __restrict__ FB_lo,
    float* __restrict__ Tb, unsigned* __restrict__ Ub_hl)
{
  const bool taskA = (blockIdx.x < 64);
  const int rb = taskA ? blockIdx.x : (blockIdx.x - 64);
  const int nrows = taskA ? 4096 : 5000;
  const float* __restrict__ Emb = taskA ? EmbA : EmbB;
  const int* __restrict__ idx = taskA ? inp : nullptr;

  const int cb = blockIdx.y;
  const int row0 = rb * 64;
  const int seg = cb >> 1;
  const int colb = (cb & 1) * 128;

  __shared__ char smL[30720];
  unsigned short* As_hi = (unsigned short*)smL;   // [64][40]
  unsigned short* As_lo = As_hi + 2560;
  unsigned short* Ws_hi = As_lo + 2560;           // [128][40]
  unsigned short* Ws_lo = Ws_hi + 5120;
  unsigned* EP = (unsigned*)smL;                  // epilogue [64][66] u32 (time-disjoint)

  const int t = threadIdx.x;
  const int w = t >> 6, l = t & 63, a = l & 15, hq = l >> 4;

  // A staging assignment: thread covers rows (t>>3) and (t>>3)+32 at kq=(t&7)
  const int arow = t >> 3, kq = t & 7;
  int gr0 = row0 + arow;      if (gr0 > nrows - 1) gr0 = nrows - 1;
  int gr1 = row0 + arow + 32; if (gr1 > nrows - 1) gr1 = nrows - 1;
  const int src0 = idx ? idx[gr0] : gr0;
  const int src1 = idx ? idx[gr1] : gr1;
  const float* ap0 = Emb + (size_t)src0 * 256 + kq * 4;
  const float* ap1 = Emb + (size_t)src1 * 256 + kq * 4;

  float4 Ac0, Ac1, An0, An1;
  uint4 Wc[4], Wn[4];

#define LOADA(ch, x0, x1) { x0 = *(const float4*)(ap0 + (ch) * 32); \
                            x1 = *(const float4*)(ap1 + (ch) * 32); }
#define LOADW(ch, WX) _Pragma("unroll") \
  for (int i = 0; i < 4; ++i) { \
    int flat = i * 256 + t; \
    int pl = flat >> 9, rem = flat & 511, n = rem >> 2, q = rem & 3; \
    const unsigned short* Wp = pl ? WT_lo : WT_hi; \
    WX[i] = *(const uint4*)&Wp[(size_t)(seg * 256 + colb + n) * 256 + (ch) * 32 + q * 8]; \
  }
#define WRITEA(x0, x1) { \
    unsigned short h0[4], l0[4], h1[4], l1[4]; \
    split_hl(x0.x, h0[0], l0[0]); split_hl(x0.y, h0[1], l0[1]); \
    split_hl(x0.z, h0[2], l0[2]); split_hl(x0.w, h0[3], l0[3]); \
    split_hl(x1.x, h1[0], l1[0]); split_hl(x1.y, h1[1], l1[1]); \
    split_hl(x1.z, h1[2], l1[2]); split_hl(x1.w, h1[3], l1[3]); \
    *(uint2*)&As_hi[arow * 40 + kq * 4] = *(uint2*)h0; \
    *(uint2*)&As_lo[arow * 40 + kq * 4] = *(uint2*)l0; \
    *(uint2*)&As_hi[(arow + 32) * 40 + kq * 4] = *(uint2*)h1; \
    *(uint2*)&As_lo[(arow + 32) * 40 + kq * 4] = *(uint2*)l1; }
#define WRITEW(WX) _Pragma("unroll") \
  for (int i = 0; i < 4; ++i) { \
    int flat = i * 256 + t; \
    int pl = flat >> 9, rem = flat & 511, n = rem >> 2, q = rem & 3; \
    *(uint4*)&(pl ? Ws_lo : Ws_hi)[n * 40 + q * 8] = WX[i]; \
  }

  f4 acc[8];
#pragma unroll
  for (int nt = 0; nt < 8; ++nt)
#pragma unroll
    for (int r = 0; r < 4; ++r) acc[nt][r] = 0.f;

  LOADA(0, Ac0, Ac1);
  LOADW(0, Wc);
  WRITEA(Ac0, Ac1);
  WRITEW(Wc);
  __syncthreads();

  for (int ch = 0; ch < 8; ++ch) {
    if (ch < 7) { LOADA(ch + 1, An0, An1); LOADW(ch + 1, Wn); }
    v8s ah = *(const v8s*)&As_hi[(w * 16 + a) * 40 + hq * 8];
    v8s al = *(const v8s*)&As_lo[(w * 16 + a) * 40 + hq * 8];
    __builtin_amdgcn_s_setprio(1);
#pragma unroll
    for (int nt = 0; nt < 8; ++nt) {
      v8s bh = *(const v8s*)&Ws_hi[(nt * 16 + a) * 40 + hq * 8];
      v8s bl = *(const v8s*)&Ws_lo[(nt * 16 + a) * 40 + hq * 8];
      acc[nt] = mm3p(ah, al, bh, bl, acc[nt]);
    }
    __builtin_amdgcn_s_setprio(0);
    __syncthreads();
    if (ch < 7) {
      WRITEA(An0, An1);
      WRITEW(Wn);
      __syncthreads();
    }
  }

  // ---- epilogue through LDS, 2 col-half passes, coalesced stores ----
  for (int p = 0; p < 2; ++p) {
    // write phase: EP[64][66] u32
#pragma unroll
    for (int nt4 = 0; nt4 < 4; ++nt4) {
      int nt = p * 4 + nt4;
      int lc = nt4 * 16 + a;
      int col = colb + p * 64 + lc;
#pragma unroll
      for (int r = 0; r < 4; ++r) {
        int lr = w * 16 + hq * 4 + r;
        float v = acc[nt][r];
        unsigned word;
        if (seg == 0)      word = pack_hl(fmaxf(v + Fb[col], 0.f));
        else if (seg == 1) word = __float_as_uint(v + Gb[col]);
        else               word = pack_hl(v);
        int ad = (seg == 2 && taskA) ? (lc * 66 + lr) : (lr * 66 + lc);
        EP[ad] = word;
      }
    }
    __syncthreads();
    // store phase
    if (seg == 1) {
      int lr = t >> 2, c0 = (t & 3) * 16;
      int grow = row0 + lr;
      if (grow < nrows) {
        float* outp = taskA ? Ta : Tb;
#pragma unroll
        for (int j = 0; j < 4; ++j) {
          float x[4];
#pragma unroll
          for (int u = 0; u < 4; ++u) x[u] = __uint_as_float(EP[lr * 66 + c0 + j * 4 + u]);
          *(float4*)&outp[(size_t)grow * 256 + colb + p * 64 + c0 + j * 4] = *(float4*)x;
        }
      }
    } else if (seg == 0 || !taskA) {
      int lr = t >> 2, c0 = (t & 3) * 16;
      int grow = row0 + lr;
      if (grow < nrows) {
        if (seg == 0) {
          unsigned short hs[16], ls[16];
#pragma unroll
          for (int j = 0; j < 16; ++j) {
            unsigned word = EP[lr * 66 + c0 + j];
            hs[j] = (unsigned short)(word & 0xffffu);
            ls[j] = (unsigned short)(word >> 16);
          }
          unsigned short* Hi = taskA ? Am_hi : FB_hi;
          unsigned short* Lo = taskA ? Am_lo : FB_lo;
          size_t o = (size_t)grow * 256 + colb + p * 64 + c0;
          *(uint4*)&Hi[o] = *(uint4*)&hs[0];
          *(uint4*)&Hi[o + 8] = *(uint4*)&hs[8];
          *(uint4*)&Lo[o] = *(uint4*)&ls[0];
          *(uint4*)&Lo[o + 8] = *(uint4*)&ls[8];
        } else {
          size_t o = (size_t)grow * 256 + colb + p * 64 + c0;
#pragma unroll
          for (int j = 0; j < 4; ++j) {
            unsigned x[4];
#pragma unroll
            for (int u = 0; u < 4; ++u) x[u] = EP[lr * 66 + c0 + j * 4 + u];
            *(uint4*)&Ub_hl[o + j * 4] = *(uint4*)x;
          }
        }
      }
    } else {
      // seg2 taskA: UaT planes [b][g][s], EP indexed [lc][lr]
      int lc = t >> 2, q = t & 3;
      int col = colb + p * 64 + lc;
      int bI = row0 >> 7, sbase = row0 & 127;
      unsigned short hs[16], ls[16];
#pragma unroll
      for (int j = 0; j < 16; ++j) {
        unsigned word = EP[lc * 66 + q * 16 + j];
        hs[j] = (unsigned short)(word & 0xffffu);
        ls[j] = (unsigned short)(word >> 16);
      }
      size_t o = ((size_t)(bI * 256 + col)) * 128 + sbase + q * 16;
      *(uint4*)&UaT_hi[o] = *(uint4*)&hs[0];
      *(uint4*)&UaT_hi[o + 8] = *(uint4*)&hs[8];
      *(uint4*)&UaT_lo[o] = *(uint4*)&ls[0];
      *(uint4*)&UaT_lo[o + 8] = *(uint4*)&ls[8];
    }
    __syncthreads();
  }
}

// ---------------------------------------------------------------------------
// Fused per-(b,c) MFMA kernel. 512 threads, 2 blocks/CU. E stride 66.
// All stagings prefetch-split: loads issued before MFMA, LDS writes after.
// ---------------------------------------------------------------------------
#define SMEM_WORDS (8448 + 9216 + 1024 + 512 + 128 + 64 + 64 + 8)
#define SMEM_BYTES (SMEM_WORDS * 4)

__global__ __launch_bounds__(512, 4) void fused_kernel(
    const int* __restrict__ cand,
    const unsigned short* __restrict__ Am_hi, const unsigned short* __restrict__ Am_lo,
    const unsigned short* __restrict__ FB_hi, const unsigned short* __restrict__ FB_lo,
    const unsigned short* __restrict__ UaT_hi, const unsigned short* __restrict__ UaT_lo,
    const unsigned* __restrict__ Ub_hl,
    const float* __restrict__ Ta, const float* __restrict__ Tb,
    float* __restrict__ V1, float* __restrict__ V2)
{
  extern __shared__ char smem[];
  unsigned* E    = (unsigned*)smem;          // [128][66] packed hi|lo
  unsigned* SH   = E + 8448;                 // 9216 words time-shared
  float* vred = (float*)(SH + 9216);         // 1024
  float* csp  = vred + 1024;                 // [8][64]
  float* rrcp = csp + 512;                   // [128]
  float* crcp = rrcp + 128;                  // [64]
  int*   cidx = (int*)(crcp + 64);           // [64]
  float* gmax = (float*)(cidx + 64);         // [8]
  unsigned short* SHs = (unsigned short*)SH;

  const int bc = ((blockIdx.x & 7) << 8) | (blockIdx.x >> 3);  // XCD swizzle
  const int b = bc >> 6, t = threadIdx.x;
  const int w = t >> 6, l = t & 63, a = l & 15, hq = l >> 4;

  if (t < 64) cidx[t] = cand[(size_t)bc * 64 + t];
  __syncthreads();

  // ---- phase 1: e = Am[b] @ FB^T; FB staged in z-halves, prefetch-split ----
  uint4 fbh[2], fbl[2];
#define LDFB(h) _Pragma("unroll") \
  for (int i = 0; i < 2; ++i) { \
    int flat = i * 512 + t; int z = flat >> 5, c = flat & 31; \
    int row = cidx[(h) * 32 + z]; \
    fbh[i] = *(const uint4*)&FB_hi[(size_t)row * 256 + c * 8]; \
    fbl[i] = *(const uint4*)&FB_lo[(size_t)row * 256 + c * 8]; \
  }
#define WRFB() _Pragma("unroll") \
  for (int i = 0; i < 2; ++i) { \
    int flat = i * 512 + t; int z = flat >> 5, c = flat & 31; \
    *(uint4*)&SHs[z * 264 + c * 8] = fbh[i]; \
    *(uint4*)&SHs[8448 + z * 264 + c * 8] = fbl[i]; \
  }

  f4 acc[4];
#pragma unroll
  for (int i = 0; i < 4; ++i)
#pragma unroll
    for (int r = 0; r < 4; ++r) acc[i][r] = 0.f;

  LDFB(0); WRFB();
  __syncthreads();
  {
    const size_t ap = ((size_t)(b * 128 + w * 16 + a)) * 256;
    for (int h = 0; h < 2; ++h) {
      if (h == 0) LDFB(1);
      __builtin_amdgcn_s_setprio(1);
#pragma unroll
      for (int ch = 0; ch < 8; ++ch) {
        int k0 = ch * 32 + hq * 8;
        v8s Ah = *(const v8s*)&Am_hi[ap + k0];
        v8s Al = *(const v8s*)&Am_lo[ap + k0];
#pragma unroll
        for (int zt2 = 0; zt2 < 2; ++zt2) {
          const int zr = (zt2 * 16 + a) * 264 + k0;
          acc[h * 2 + zt2] = mm3p(Ah, Al, *(const v8s*)&SHs[zr],
                                  *(const v8s*)&SHs[8448 + zr], acc[h * 2 + zt2]);
        }
      }
      __builtin_amdgcn_s_setprio(0);
      __syncthreads();
      if (h == 0) { WRFB(); __syncthreads(); }
    }
  }

  // ---- softmax: global max; E = exp(e-M); rrcp/crcp ----
  {
    float m = -1e30f;
#pragma unroll
    for (int zt = 0; zt < 4; ++zt)
#pragma unroll
      for (int r = 0; r < 4; ++r) m = fmaxf(m, acc[zt][r]);
#pragma unroll
    for (int d = 1; d < 64; d <<= 1) m = fmaxf(m, __shfl_xor(m, d));
    if (l == 0) gmax[w] = m;
    __syncthreads();
    float M = gmax[0];
#pragma unroll
    for (int q = 1; q < 8; ++q) M = fmaxf(M, gmax[q]);

#pragma unroll
    for (int zt = 0; zt < 4; ++zt)
#pragma unroll
      for (int r = 0; r < 4; ++r) acc[zt][r] = __expf(acc[zt][r] - M);

#pragma unroll
    for (int r = 0; r < 4; ++r) {
      float rs = acc[0][r] + acc[1][r] + acc[2][r] + acc[3][r];
      rs += __shfl_xor(rs, 1); rs += __shfl_xor(rs, 2);
      rs += __shfl_xor(rs, 4); rs += __shfl_xor(rs, 8);
      if (a == 0) rrcp[w * 16 + hq * 4 + r] = 1.f / rs;
    }
#pragma unroll
    for (int zt = 0; zt < 4; ++zt) {
      float c = acc[zt][0] + acc[zt][1] + acc[zt][2] + acc[zt][3];
      c += __shfl_xor(c, 16); c += __shfl_xor(c, 32);
      if (l < 16) csp[w * 64 + zt * 16 + l] = c;
    }
#pragma unroll
    for (int zt = 0; zt < 4; ++zt)
#pragma unroll
      for (int r = 0; r < 4; ++r)
        E[(w * 16 + hq * 4 + r) * 66 + zt * 16 + a] = pack_hl(acc[zt][r]);
    __syncthreads();
    if (t < 64) {
      float s = 0.f;
#pragma unroll
      for (int q = 0; q < 8; ++q) s += csp[q * 64 + t];
      crcp[t] = 1.f / s;
    }
    __syncthreads();
  }

  // ---- phase 3a: P2 = Et @ Ua; UaT staged per g-quarter, prefetch-split ----
  {
    const int zt = w >> 1, gp = w & 1;
    HL af[4];
#pragma unroll
    for (int ch = 0; ch < 4; ++ch) {
      unsigned q[8];
#pragma unroll
      for (int j = 0; j < 8; ++j)
        q[j] = E[(ch * 32 + hq * 8 + j) * 66 + zt * 16 + a];
      uint4 q0; q0.x = q[0]; q0.y = q[1]; q0.z = q[2]; q0.w = q[3];
      uint4 q1; q1.x = q[4]; q1.y = q[5]; q1.z = q[6]; q1.w = q[7];
      af[ch] = unpack8(q0, q1);
    }
    float crz[4]; const float* tbp[4];
#pragma unroll
    for (int r = 0; r < 4; ++r) {
      int z = zt * 16 + hq * 4 + r;
      crz[r] = crcp[z];
      tbp[r] = Tb + (size_t)cidx[z] * 256;
    }
    uint4 uq[4];
#define LDUA(Q) _Pragma("unroll") \
    for (int i = 0; i < 4; ++i) { \
      int idx4 = i * 512 + t; \
      int pl = idx4 >> 10, rem = idx4 & 1023, g = rem >> 4, q = rem & 15; \
      const unsigned short* up = pl ? UaT_lo : UaT_hi; \
      uq[i] = *(const uint4*)&up[((size_t)(b * 256 + (Q) * 64 + g)) * 128 + q * 8]; \
    }
#define WRUA() _Pragma("unroll") \
    for (int i = 0; i < 4; ++i) { \
      int idx4 = i * 512 + t; \
      int pl = idx4 >> 10, rem = idx4 & 1023, g = rem >> 4, q = rem & 15; \
      *(uint4*)&SHs[pl * 8704 + g * 136 + q * 8] = uq[i]; \
    }
    LDUA(0); WRUA();
    __syncthreads();
    for (int Q = 0; Q < 4; ++Q) {
      if (Q < 3) LDUA(Q + 1);
      __builtin_amdgcn_s_setprio(1);
#pragma unroll
      for (int gt2 = 0; gt2 < 2; ++gt2) {
        int gloc = (gp * 2 + gt2) * 16 + a;
        int gg = Q * 64 + gloc;
        f4 c = {0.f, 0.f, 0.f, 0.f};
#pragma unroll
        for (int ch = 0; ch < 4; ++ch) {
          int k0 = ch * 32 + hq * 8;
          c = mm3h(af[ch], *(const v8s*)&SHs[gloc * 136 + k0],
                   *(const v8s*)&SHs[8704 + gloc * 136 + k0], c);
        }
        float sv = 0.f;
#pragma unroll
        for (int r = 0; r < 4; ++r)
          sv += fmaxf(fmaf(c[r], crz[r], tbp[r][gg]), 0.f);
        sv += __shfl_xor(sv, 16); sv += __shfl_xor(sv, 32);
        if (l < 16) vred[zt * 256 + gg] = sv;
      }
      __builtin_amdgcn_s_setprio(0);
      __syncthreads();
      if (Q < 3) { WRUA(); __syncthreads(); }
    }
    if (t < 256)
      V2[(size_t)bc * 256 + t] = vred[t] + vred[256 + t] + vred[512 + t] + vred[768 + t];
  }

  // ---- phase 3b: P1 = E @ Ub; UbT staged per g-half, prefetch-split ----
  {
    unsigned ub0[8], ub1[8];
#define LDUB(h) _Pragma("unroll") \
    for (int i = 0; i < 8; ++i) { \
      int flat = i * 512 + t; \
      int c2 = flat & 3, g = (flat >> 2) & 127; \
      int zp = i * 4 + c2; \
      ub0[i] = Ub_hl[(size_t)cidx[zp * 2]     * 256 + (h) * 128 + g]; \
      ub1[i] = Ub_hl[(size_t)cidx[zp * 2 + 1] * 256 + (h) * 128 + g]; \
    }
#define WRUB() _Pragma("unroll") \
    for (int i = 0; i < 8; ++i) { \
      int flat = i * 512 + t; \
      int c2 = flat & 3, g = (flat >> 2) & 127; \
      int zp = i * 4 + c2; \
      SH[g * 36 + zp]        = (ub0[i] & 0xffffu) | (ub1[i] << 16); \
      SH[4608 + g * 36 + zp] = (ub0[i] >> 16) | (ub1[i] & 0xffff0000u); \
    }
    LDUB(0); WRUB();
    __syncthreads();

    HL af1[2];
#pragma unroll
    for (int ch = 0; ch < 2; ++ch) {
      const unsigned* p = E + (w * 16 + a) * 66 + ch * 32 + hq * 8;
      af1[ch] = unpack8(*(const uint4*)p, *(const uint4*)(p + 4));
    }
    float rr[4]; const float* tap[4];
#pragma unroll
    for (int r = 0; r < 4; ++r) {
      int s = w * 16 + hq * 4 + r;
      rr[r] = rrcp[s];
      tap[r] = Ta + ((size_t)(b * 128 + s)) * 256;
    }
    for (int h = 0; h < 2; ++h) {
      if (h == 0) LDUB(1);
      __builtin_amdgcn_s_setprio(1);
#pragma unroll
      for (int gt = 0; gt < 8; ++gt) {
        int g = gt * 16 + a;
        f4 c = {0.f, 0.f, 0.f, 0.f};
#pragma unroll
        for (int ch = 0; ch < 2; ++ch) {
          int k0 = ch * 32 + hq * 8;
          c = mm3h(af1[ch], *(const v8s*)&SHs[g * 72 + k0],
                   *(const v8s*)&SHs[9216 + g * 72 + k0], c);
        }
        float sv = 0.f;
#pragma unroll
        for (int r = 0; r < 4; ++r)
          sv += fmaxf(fmaf(c[r], rr[r], tap[r][h * 128 + g]), 0.f);
        sv += __shfl_xor(sv, 16); sv += __shfl_xor(sv, 32);
        if (l < 16) vred[w * 128 + g] = sv;
      }
      __builtin_amdgcn_s_setprio(0);
      __syncthreads();
      if (t < 128) {
        float s = 0.f;
#pragma unroll
        for (int q = 0; q < 8; ++q) s += vred[q * 128 + t];
        V1[(size_t)bc * 256 + h * 128 + t] = s;
      }
      if (h == 0) { __syncthreads(); WRUB(); __syncthreads(); }
    }
  }
}

// ---------------------------------------------------------------------------
// y[bc] = V1[bc]·HW[0:256] + V2[bc]·HW[256:512] + Hb
// ---------------------------------------------------------------------------
__global__ __launch_bounds__(256) void final_kernel(
    const float* __restrict__ V1, const float* __restrict__ V2,
    const float* __restrict__ HW, const float* __restrict__ Hb,
    float* __restrict__ y)
{
  const int t = threadIdx.x;
  const int w = t >> 6, l = t & 63;
  const int bc = blockIdx.x * 4 + w;
  float4 v1 = *(const float4*)&V1[(size_t)bc * Dc + l * 4];
  float4 h1 = *(const float4*)&HW[l * 4];
  float4 v2 = *(const float4*)&V2[(size_t)bc * Dc + l * 4];
  float4 h2 = *(const float4*)&HW[Dc + l * 4];
  float sum = v1.x * h1.x + v1.y * h1.y + v1.z * h1.z + v1.w * h1.w
            + v2.x * h2.x + v2.y * h2.y + v2.z * h2.z + v2.w * h2.w;
#pragma unroll
  for (int off = 32; off > 0; off >>= 1) sum += __shfl_down(sum, off);
  if (l == 0) y[bc] = sum + Hb[0];
}

extern "C" void kernel_launch(void* const* d_in, const int* in_sizes, int n_in,
                              void* d_out, int out_size, void* d_ws, size_t ws_size,
                              hipStream_t stream) {
  (void)in_sizes; (void)n_in; (void)out_size; (void)ws_size;
  const int*   inp  = (const int*)d_in[0];
  const int*   cand = (const int*)d_in[1];
  const float* EmbA = (const float*)d_in[4];
  const float* EmbB = (const float*)d_in[5];
  const float* FW   = (const float*)d_in[6];
  const float* Fb   = (const float*)d_in[7];
  const float* GW   = (const float*)d_in[8];
  const float* Gb   = (const float*)d_in[9];
  const float* HW   = (const float*)d_in[10];
  const float* Hb   = (const float*)d_in[11];
  float* y = (float*)d_out;

  const size_t nA = (size_t)Bc * Sc * Dc;   // 1,048,576 elems
  const size_t nB = (size_t)VOc * Dc;       // 1,280,000 elems
  const size_t nV = (size_t)Bc * Cc * Dc;   //   524,288 elems
  const size_t nW = (size_t)768 * 256;      //   196,608 elems
  char* ws = (char*)d_ws;
  unsigned short* Am_hi = (unsigned short*)ws;              ws += nA * 2;
  unsigned short* Am_lo = (unsigned short*)ws;              ws += nA * 2;
  unsigned short* FB_hi = (unsigned short*)ws;              ws += nB * 2;
  unsigned short* FB_lo = (unsigned short*)ws;              ws += nB * 2;
  unsigned short* UaT_hi = (unsigned short*)ws;             ws += nA * 2;
  unsigned short* UaT_lo = (unsigned short*)ws;             ws += nA * 2;
  unsigned*       Ub_hl  = (unsigned*)ws;                   ws += nB * 4;
  float*          Ta     = (float*)ws;                      ws += nA * 4;
  float*          Tb     = (float*)ws;                      ws += nB * 4;
  float*          V1     = (float*)ws;                      ws += nV * 4;
  float*          V2     = (float*)ws;                      ws += nV * 4;
  unsigned short* WT_hi  = (unsigned short*)ws;             ws += nW * 2;
  unsigned short* WT_lo  = (unsigned short*)ws;             // total ~33.4 MB

  hipFuncSetAttribute((const void*)fused_kernel,
                      hipFuncAttributeMaxDynamicSharedMemorySize, SMEM_BYTES);

  prep_kernel<<<768, 256, 0, stream>>>(FW, GW, WT_hi, WT_lo);
  transform_kernel<<<dim3(143, 6), 256, 0, stream>>>(
      EmbA, inp, EmbB, WT_hi, WT_lo, Fb, Gb,
      Am_hi, Am_lo, Ta, UaT_hi, UaT_lo, FB_hi, FB_lo, Tb, Ub_hl);
  fused_kernel<<<Bc * Cc, 512, SMEM_BYTES, stream>>>(
      cand, Am_hi, Am_lo, FB_hi, FB_lo, UaT_hi, UaT_lo, Ub_hl, Ta, Tb, V1, V2);
  final_kernel<<<(Bc * Cc) / 4, 256, 0, stream>>>(V1, V2, HW, Hb, y);
}

// Round 9
// 291.097 us; speedup vs baseline: 1.2067x; 1.2067x over previous
//
#include <hip/hip_runtime.h>
#include <hip/hip_bf16.h>
#include <math.h>

#define Bc 32
#define Cc 64
#define Sc 128
#define Zc 64
#define Dc 256
#define VOc 5000

typedef __attribute__((ext_vector_type(8))) short v8s;   // 8 bf16 = 4 VGPR MFMA frag
typedef __attribute__((ext_vector_type(4))) float f4;    // 16x16 accum

union FQ { uint4 q; v8s s; };
struct HL { v8s hi, lo; };

__device__ __forceinline__ unsigned short bf_bits(__hip_bfloat16 h) {
  union { __hip_bfloat16 b; unsigned short u; } cv; cv.b = h; return cv.u;
}

__device__ __forceinline__ void split_hl(float x, unsigned short& h, unsigned short& l) {
  __hip_bfloat16 hh = __float2bfloat16(x);
  float hf = __bfloat162float(hh);
  __hip_bfloat16 ll = __float2bfloat16(x - hf);
  h = bf_bits(hh); l = bf_bits(ll);
}

__device__ __forceinline__ unsigned pack_hl(float x) {
  unsigned short h, l; split_hl(x, h, l);
  return (unsigned)h | ((unsigned)l << 16);
}

__device__ __forceinline__ HL unpack8(uint4 q0, uint4 q1) {
  FQ h, l;
  h.q.x = __builtin_amdgcn_perm(q0.y, q0.x, 0x05040100u);
  h.q.y = __builtin_amdgcn_perm(q0.w, q0.z, 0x05040100u);
  h.q.z = __builtin_amdgcn_perm(q1.y, q1.x, 0x05040100u);
  h.q.w = __builtin_amdgcn_perm(q1.w, q1.z, 0x05040100u);
  l.q.x = __builtin_amdgcn_perm(q0.y, q0.x, 0x07060302u);
  l.q.y = __builtin_amdgcn_perm(q0.w, q0.z, 0x07060302u);
  l.q.z = __builtin_amdgcn_perm(q1.y, q1.x, 0x07060302u);
  l.q.w = __builtin_amdgcn_perm(q1.w, q1.z, 0x07060302u);
  HL r; r.hi = h.s; r.lo = l.s; return r;
}

__device__ __forceinline__ f4 mm3p(v8s ah, v8s al, v8s bh, v8s bl, f4 c) {
  c = __builtin_amdgcn_mfma_f32_16x16x32_bf16(ah, bh, c, 0, 0, 0);
  c = __builtin_amdgcn_mfma_f32_16x16x32_bf16(ah, bl, c, 0, 0, 0);
  c = __builtin_amdgcn_mfma_f32_16x16x32_bf16(al, bh, c, 0, 0, 0);
  return c;
}
__device__ __forceinline__ f4 mm3h(const HL& A, v8s bh, v8s bl, f4 c) {
  return mm3p(A.hi, A.lo, bh, bl, c);
}

// ---------------------------------------------------------------------------
// prep: WT[j][k] = Wseg[k][n] transposed + hi/lo split. j = seg*256+n.
// ---------------------------------------------------------------------------
__global__ __launch_bounds__(256) void prep_kernel(
    const float* __restrict__ FW, const float* __restrict__ GW,
    unsigned short* __restrict__ WT_hi, unsigned short* __restrict__ WT_lo)
{
  const int j = blockIdx.x, t = threadIdx.x;
  const int seg = j >> 8, n = j & 255;
  float v;
  if (seg == 0) v = FW[(size_t)t * 256 + n];
  else if (seg == 1) v = GW[(size_t)t * 256 + n];
  else v = GW[(size_t)(256 + t) * 256 + n];
  unsigned short h, l; split_hl(v, h, l);
  WT_hi[(size_t)j * 256 + t] = h;
  WT_lo[(size_t)j * 256 + t] = l;
}

// ---------------------------------------------------------------------------
// Transform (MFMA 3-term, software-pipelined staging, LDS-coalesced epilogue).
// 64 rows x 128 cols per block; K=256 in 8 chunks of 32.  (as R8)
// ---------------------------------------------------------------------------
__global__ __launch_bounds__(256, 4) void transform_kernel(
    const float* __restrict__ EmbA, const int* __restrict__ inp,
    const float* __restrict__ EmbB,
    const unsigned short* __restrict__ WT_hi, const unsigned short* __restrict__ WT_lo,
    const float* __restrict__ Fb, const float* __restrict__ Gb,
    unsigned short* __restrict__ Am_hi, unsigned short* __restrict__ Am_lo,
    float* __restrict__ Ta,
    unsigned short* __restrict__ UaT_hi, unsigned short* __restrict__ UaT_lo,
    unsigned short* __restrict__ FB_hi, unsigned short* __restrict__ FB_lo,
    float* __restrict__ Tb, unsigned* __restrict__ Ub_hl)
{
  const bool taskA = (blockIdx.x < 64);
  const int rb = taskA ? blockIdx.x : (blockIdx.x - 64);
  const int nrows = taskA ? 4096 : 5000;
  const float* __restrict__ Emb = taskA ? EmbA : EmbB;
  const int* __restrict__ idx = taskA ? inp : nullptr;

  const int cb = blockIdx.y;
  const int row0 = rb * 64;
  const int seg = cb >> 1;
  const int colb = (cb & 1) * 128;

  __shared__ char smL[30720];
  unsigned short* As_hi = (unsigned short*)smL;   // [64][40]
  unsigned short* As_lo = As_hi + 2560;
  unsigned short* Ws_hi = As_lo + 2560;           // [128][40]
  unsigned short* Ws_lo = Ws_hi + 5120;
  unsigned* EP = (unsigned*)smL;                  // epilogue [64][66] u32 (time-disjoint)

  const int t = threadIdx.x;
  const int w = t >> 6, l = t & 63, a = l & 15, hq = l >> 4;

  const int arow = t >> 3, kq = t & 7;
  int gr0 = row0 + arow;      if (gr0 > nrows - 1) gr0 = nrows - 1;
  int gr1 = row0 + arow + 32; if (gr1 > nrows - 1) gr1 = nrows - 1;
  const int src0 = idx ? idx[gr0] : gr0;
  const int src1 = idx ? idx[gr1] : gr1;
  const float* ap0 = Emb + (size_t)src0 * 256 + kq * 4;
  const float* ap1 = Emb + (size_t)src1 * 256 + kq * 4;

  float4 Ac0, Ac1, An0, An1;
  uint4 Wc[4], Wn[4];

#define LOADA(ch, x0, x1) { x0 = *(const float4*)(ap0 + (ch) * 32); \
                            x1 = *(const float4*)(ap1 + (ch) * 32); }
#define LOADW(ch, WX) _Pragma("unroll") \
  for (int i = 0; i < 4; ++i) { \
    int flat = i * 256 + t; \
    int pl = flat >> 9, rem = flat & 511, n = rem >> 2, q = rem & 3; \
    const unsigned short* Wp = pl ? WT_lo : WT_hi; \
    WX[i] = *(const uint4*)&Wp[(size_t)(seg * 256 + colb + n) * 256 + (ch) * 32 + q * 8]; \
  }
#define WRITEA(x0, x1) { \
    unsigned short h0[4], l0[4], h1[4], l1[4]; \
    split_hl(x0.x, h0[0], l0[0]); split_hl(x0.y, h0[1], l0[1]); \
    split_hl(x0.z, h0[2], l0[2]); split_hl(x0.w, h0[3], l0[3]); \
    split_hl(x1.x, h1[0], l1[0]); split_hl(x1.y, h1[1], l1[1]); \
    split_hl(x1.z, h1[2], l1[2]); split_hl(x1.w, h1[3], l1[3]); \
    *(uint2*)&As_hi[arow * 40 + kq * 4] = *(uint2*)h0; \
    *(uint2*)&As_lo[arow * 40 + kq * 4] = *(uint2*)l0; \
    *(uint2*)&As_hi[(arow + 32) * 40 + kq * 4] = *(uint2*)h1; \
    *(uint2*)&As_lo[(arow + 32) * 40 + kq * 4] = *(uint2*)l1; }
#define WRITEW(WX) _Pragma("unroll") \
  for (int i = 0; i < 4; ++i) { \
    int flat = i * 256 + t; \
    int pl = flat >> 9, rem = flat & 511, n = rem >> 2, q = rem & 3; \
    *(uint4*)&(pl ? Ws_lo : Ws_hi)[n * 40 + q * 8] = WX[i]; \
  }

  f4 acc[8];
#pragma unroll
  for (int nt = 0; nt < 8; ++nt)
#pragma unroll
    for (int r = 0; r < 4; ++r) acc[nt][r] = 0.f;

  LOADA(0, Ac0, Ac1);
  LOADW(0, Wc);
  WRITEA(Ac0, Ac1);
  WRITEW(Wc);
  __syncthreads();

  for (int ch = 0; ch < 8; ++ch) {
    if (ch < 7) { LOADA(ch + 1, An0, An1); LOADW(ch + 1, Wn); }
    v8s ah = *(const v8s*)&As_hi[(w * 16 + a) * 40 + hq * 8];
    v8s al = *(const v8s*)&As_lo[(w * 16 + a) * 40 + hq * 8];
    __builtin_amdgcn_s_setprio(1);
#pragma unroll
    for (int nt = 0; nt < 8; ++nt) {
      v8s bh = *(const v8s*)&Ws_hi[(nt * 16 + a) * 40 + hq * 8];
      v8s bl = *(const v8s*)&Ws_lo[(nt * 16 + a) * 40 + hq * 8];
      acc[nt] = mm3p(ah, al, bh, bl, acc[nt]);
    }
    __builtin_amdgcn_s_setprio(0);
    __syncthreads();
    if (ch < 7) {
      WRITEA(An0, An1);
      WRITEW(Wn);
      __syncthreads();
    }
  }

  // ---- epilogue through LDS, 2 col-half passes, coalesced stores ----
  for (int p = 0; p < 2; ++p) {
#pragma unroll
    for (int nt4 = 0; nt4 < 4; ++nt4) {
      int nt = p * 4 + nt4;
      int lc = nt4 * 16 + a;
      int col = colb + p * 64 + lc;
#pragma unroll
      for (int r = 0; r < 4; ++r) {
        int lr = w * 16 + hq * 4 + r;
        float v = acc[nt][r];
        unsigned word;
        if (seg == 0)      word = pack_hl(fmaxf(v + Fb[col], 0.f));
        else if (seg == 1) word = __float_as_uint(v + Gb[col]);
        else               word = pack_hl(v);
        int ad = (seg == 2 && taskA) ? (lc * 66 + lr) : (lr * 66 + lc);
        EP[ad] = word;
      }
    }
    __syncthreads();
    if (seg == 1) {
      int lr = t >> 2, c0 = (t & 3) * 16;
      int grow = row0 + lr;
      if (grow < nrows) {
        float* outp = taskA ? Ta : Tb;
#pragma unroll
        for (int j = 0; j < 4; ++j) {
          float x[4];
#pragma unroll
          for (int u = 0; u < 4; ++u) x[u] = __uint_as_float(EP[lr * 66 + c0 + j * 4 + u]);
          *(float4*)&outp[(size_t)grow * 256 + colb + p * 64 + c0 + j * 4] = *(float4*)x;
        }
      }
    } else if (seg == 0 || !taskA) {
      int lr = t >> 2, c0 = (t & 3) * 16;
      int grow = row0 + lr;
      if (grow < nrows) {
        if (seg == 0) {
          unsigned short hs[16], ls[16];
#pragma unroll
          for (int j = 0; j < 16; ++j) {
            unsigned word = EP[lr * 66 + c0 + j];
            hs[j] = (unsigned short)(word & 0xffffu);
            ls[j] = (unsigned short)(word >> 16);
          }
          unsigned short* Hi = taskA ? Am_hi : FB_hi;
          unsigned short* Lo = taskA ? Am_lo : FB_lo;
          size_t o = (size_t)grow * 256 + colb + p * 64 + c0;
          *(uint4*)&Hi[o] = *(uint4*)&hs[0];
          *(uint4*)&Hi[o + 8] = *(uint4*)&hs[8];
          *(uint4*)&Lo[o] = *(uint4*)&ls[0];
          *(uint4*)&Lo[o + 8] = *(uint4*)&ls[8];
        } else {
          size_t o = (size_t)grow * 256 + colb + p * 64 + c0;
#pragma unroll
          for (int j = 0; j < 4; ++j) {
            unsigned x[4];
#pragma unroll
            for (int u = 0; u < 4; ++u) x[u] = EP[lr * 66 + c0 + j * 4 + u];
            *(uint4*)&Ub_hl[o + j * 4] = *(uint4*)x;
          }
        }
      }
    } else {
      int lc = t >> 2, q = t & 3;
      int col = colb + p * 64 + lc;
      int bI = row0 >> 7, sbase = row0 & 127;
      unsigned short hs[16], ls[16];
#pragma unroll
      for (int j = 0; j < 16; ++j) {
        unsigned word = EP[lc * 66 + q * 16 + j];
        hs[j] = (unsigned short)(word & 0xffffu);
        ls[j] = (unsigned short)(word >> 16);
      }
      size_t o = ((size_t)(bI * 256 + col)) * 128 + sbase + q * 16;
      *(uint4*)&UaT_hi[o] = *(uint4*)&hs[0];
      *(uint4*)&UaT_hi[o + 8] = *(uint4*)&hs[8];
      *(uint4*)&UaT_lo[o] = *(uint4*)&ls[0];
      *(uint4*)&UaT_lo[o + 8] = *(uint4*)&ls[8];
    }
    __syncthreads();
  }
}

// ---------------------------------------------------------------------------
// Fused per-(b,c) MFMA kernel. 512 threads, 2 blocks/CU. E stride 66.
// Inline staging (R7 structure — no cross-barrier register prefetch).
// ---------------------------------------------------------------------------
#define SMEM_WORDS (8448 + 9216 + 1024 + 512 + 128 + 64 + 64 + 8)
#define SMEM_BYTES (SMEM_WORDS * 4)

__global__ __launch_bounds__(512, 4) void fused_kernel(
    const int* __restrict__ cand,
    const unsigned short* __restrict__ Am_hi, const unsigned short* __restrict__ Am_lo,
    const unsigned short* __restrict__ FB_hi, const unsigned short* __restrict__ FB_lo,
    const unsigned short* __restrict__ UaT_hi, const unsigned short* __restrict__ UaT_lo,
    const unsigned* __restrict__ Ub_hl,
    const float* __restrict__ Ta, const float* __restrict__ Tb,
    float* __restrict__ V1, float* __restrict__ V2)
{
  extern __shared__ char smem[];
  unsigned* E    = (unsigned*)smem;          // [128][66] packed hi|lo
  unsigned* SH   = E + 8448;                 // 9216 words time-shared
  float* vred = (float*)(SH + 9216);         // 1024
  float* csp  = vred + 1024;                 // [8][64]
  float* rrcp = csp + 512;                   // [128]
  float* crcp = rrcp + 128;                  // [64]
  int*   cidx = (int*)(crcp + 64);           // [64]
  float* gmax = (float*)(cidx + 64);         // [8]
  unsigned short* SHs = (unsigned short*)SH;

  const int bc = ((blockIdx.x & 7) << 8) | (blockIdx.x >> 3);  // XCD swizzle
  const int b = bc >> 6, t = threadIdx.x;
  const int w = t >> 6, l = t & 63, a = l & 15, hq = l >> 4;

  if (t < 64) cidx[t] = cand[(size_t)bc * 64 + t];
  __syncthreads();

  // ---- phase 1: e = Am[b] @ FB^T; A preloaded, FB staged in z-halves ----
  uint4 Ah4[8], Al4[8];
  {
    const size_t ap = ((size_t)(b * 128 + w * 16 + a)) * 256;
#pragma unroll
    for (int ch = 0; ch < 8; ++ch) {
      Ah4[ch] = *(const uint4*)&Am_hi[ap + ch * 32 + hq * 8];
      Al4[ch] = *(const uint4*)&Am_lo[ap + ch * 32 + hq * 8];
    }
  }
  f4 acc[4];
#pragma unroll
  for (int i = 0; i < 4; ++i)
#pragma unroll
    for (int r = 0; r < 4; ++r) acc[i][r] = 0.f;

  for (int h = 0; h < 2; ++h) {
#pragma unroll
    for (int i = 0; i < 2; ++i) {
      int flat = i * 512 + t;
      int z = flat >> 5, c = flat & 31;
      int row = cidx[h * 32 + z];
      *(uint4*)&SHs[z * 264 + c * 8]        = *(const uint4*)&FB_hi[(size_t)row * 256 + c * 8];
      *(uint4*)&SHs[8448 + z * 264 + c * 8] = *(const uint4*)&FB_lo[(size_t)row * 256 + c * 8];
    }
    __syncthreads();
    __builtin_amdgcn_s_setprio(1);
#pragma unroll
    for (int ch = 0; ch < 8; ++ch) {
      int k0 = ch * 32 + hq * 8;
      FQ ahf, alf; ahf.q = Ah4[ch]; alf.q = Al4[ch];
#pragma unroll
      for (int zt2 = 0; zt2 < 2; ++zt2) {
        const int zr = (zt2 * 16 + a) * 264 + k0;
        acc[h * 2 + zt2] = mm3p(ahf.s, alf.s, *(const v8s*)&SHs[zr],
                                *(const v8s*)&SHs[8448 + zr], acc[h * 2 + zt2]);
      }
    }
    __builtin_amdgcn_s_setprio(0);
    __syncthreads();
  }

  // ---- softmax: global max; E = exp(e-M); rrcp/crcp ----
  {
    float m = -1e30f;
#pragma unroll
    for (int zt = 0; zt < 4; ++zt)
#pragma unroll
      for (int r = 0; r < 4; ++r) m = fmaxf(m, acc[zt][r]);
#pragma unroll
    for (int d = 1; d < 64; d <<= 1) m = fmaxf(m, __shfl_xor(m, d));
    if (l == 0) gmax[w] = m;
    __syncthreads();
    float M = gmax[0];
#pragma unroll
    for (int q = 1; q < 8; ++q) M = fmaxf(M, gmax[q]);

#pragma unroll
    for (int zt = 0; zt < 4; ++zt)
#pragma unroll
      for (int r = 0; r < 4; ++r) acc[zt][r] = __expf(acc[zt][r] - M);

#pragma unroll
    for (int r = 0; r < 4; ++r) {
      float rs = acc[0][r] + acc[1][r] + acc[2][r] + acc[3][r];
      rs += __shfl_xor(rs, 1); rs += __shfl_xor(rs, 2);
      rs += __shfl_xor(rs, 4); rs += __shfl_xor(rs, 8);
      if (a == 0) rrcp[w * 16 + hq * 4 + r] = 1.f / rs;
    }
#pragma unroll
    for (int zt = 0; zt < 4; ++zt) {
      float c = acc[zt][0] + acc[zt][1] + acc[zt][2] + acc[zt][3];
      c += __shfl_xor(c, 16); c += __shfl_xor(c, 32);
      if (l < 16) csp[w * 64 + zt * 16 + l] = c;
    }
#pragma unroll
    for (int zt = 0; zt < 4; ++zt)
#pragma unroll
      for (int r = 0; r < 4; ++r)
        E[(w * 16 + hq * 4 + r) * 66 + zt * 16 + a] = pack_hl(acc[zt][r]);
    __syncthreads();
    if (t < 64) {
      float s = 0.f;
#pragma unroll
      for (int q = 0; q < 8; ++q) s += csp[q * 64 + t];
      crcp[t] = 1.f / s;
    }
    __syncthreads();
  }

  // ---- phase 3a: P2 = Et @ Ua; UaT staged per g-quarter (inline) ----
  {
    const int zt = w >> 1, gp = w & 1;
    HL af[4];
#pragma unroll
    for (int ch = 0; ch < 4; ++ch) {
      unsigned q[8];
#pragma unroll
      for (int j = 0; j < 8; ++j)
        q[j] = E[(ch * 32 + hq * 8 + j) * 66 + zt * 16 + a];
      uint4 q0; q0.x = q[0]; q0.y = q[1]; q0.z = q[2]; q0.w = q[3];
      uint4 q1; q1.x = q[4]; q1.y = q[5]; q1.z = q[6]; q1.w = q[7];
      af[ch] = unpack8(q0, q1);
    }
    float crz[4]; const float* tbp[4];
#pragma unroll
    for (int r = 0; r < 4; ++r) {
      int z = zt * 16 + hq * 4 + r;
      crz[r] = crcp[z];
      tbp[r] = Tb + (size_t)cidx[z] * 256;
    }
    for (int Q = 0; Q < 4; ++Q) {
#pragma unroll
      for (int i = 0; i < 4; ++i) {
        int idx4 = i * 512 + t;
        int pl = idx4 >> 10, rem = idx4 & 1023, g = rem >> 4, q = rem & 15;
        const unsigned short* up = pl ? UaT_lo : UaT_hi;
        *(uint4*)&SHs[pl * 8704 + g * 136 + q * 8] =
            *(const uint4*)&up[((size_t)(b * 256 + Q * 64 + g)) * 128 + q * 8];
      }
      __syncthreads();
      __builtin_amdgcn_s_setprio(1);
#pragma unroll
      for (int gt2 = 0; gt2 < 2; ++gt2) {
        int gloc = (gp * 2 + gt2) * 16 + a;
        int gg = Q * 64 + gloc;
        f4 c = {0.f, 0.f, 0.f, 0.f};
#pragma unroll
        for (int ch = 0; ch < 4; ++ch) {
          int k0 = ch * 32 + hq * 8;
          c = mm3h(af[ch], *(const v8s*)&SHs[gloc * 136 + k0],
                   *(const v8s*)&SHs[8704 + gloc * 136 + k0], c);
        }
        float sv = 0.f;
#pragma unroll
        for (int r = 0; r < 4; ++r)
          sv += fmaxf(fmaf(c[r], crz[r], tbp[r][gg]), 0.f);
        sv += __shfl_xor(sv, 16); sv += __shfl_xor(sv, 32);
        if (l < 16) vred[zt * 256 + gg] = sv;
      }
      __builtin_amdgcn_s_setprio(0);
      __syncthreads();
    }
    if (t < 256)
      V2[(size_t)bc * 256 + t] = vred[t] + vred[256 + t] + vred[512 + t] + vred[768 + t];
  }

  // ---- phase 3b: P1 = E @ Ub; UbT staged per g-half (inline, conflict-fixed) ----
  {
    HL af1[2];
#pragma unroll
    for (int ch = 0; ch < 2; ++ch) {
      const unsigned* p = E + (w * 16 + a) * 66 + ch * 32 + hq * 8;
      af1[ch] = unpack8(*(const uint4*)p, *(const uint4*)(p + 4));
    }
    float rr[4]; const float* tap[4];
#pragma unroll
    for (int r = 0; r < 4; ++r) {
      int s = w * 16 + hq * 4 + r;
      rr[r] = rrcp[s];
      tap[r] = Ta + ((size_t)(b * 128 + s)) * 256;
    }
    for (int h = 0; h < 2; ++h) {
#pragma unroll
      for (int i = 0; i < 8; ++i) {
        int flat = i * 512 + t;
        int c2 = flat & 3, g = (flat >> 2) & 127;
        int zp = i * 4 + c2;
        unsigned p0 = Ub_hl[(size_t)cidx[zp * 2]     * 256 + h * 128 + g];
        unsigned p1 = Ub_hl[(size_t)cidx[zp * 2 + 1] * 256 + h * 128 + g];
        SH[g * 36 + zp]        = (p0 & 0xffffu) | (p1 << 16);
        SH[4608 + g * 36 + zp] = (p0 >> 16) | (p1 & 0xffff0000u);
      }
      __syncthreads();
      __builtin_amdgcn_s_setprio(1);
#pragma unroll
      for (int gt = 0; gt < 8; ++gt) {
        int g = gt * 16 + a;
        f4 c = {0.f, 0.f, 0.f, 0.f};
#pragma unroll
        for (int ch = 0; ch < 2; ++ch) {
          int k0 = ch * 32 + hq * 8;
          c = mm3h(af1[ch], *(const v8s*)&SHs[g * 72 + k0],
                   *(const v8s*)&SHs[9216 + g * 72 + k0], c);
        }
        float sv = 0.f;
#pragma unroll
        for (int r = 0; r < 4; ++r)
          sv += fmaxf(fmaf(c[r], rr[r], tap[r][h * 128 + g]), 0.f);
        sv += __shfl_xor(sv, 16); sv += __shfl_xor(sv, 32);
        if (l < 16) vred[w * 128 + g] = sv;
      }
      __builtin_amdgcn_s_setprio(0);
      __syncthreads();
      if (t < 128) {
        float s = 0.f;
#pragma unroll
        for (int q = 0; q < 8; ++q) s += vred[q * 128 + t];
        V1[(size_t)bc * 256 + h * 128 + t] = s;
      }
    }
  }
}

// ---------------------------------------------------------------------------
// y[bc] = V1[bc]·HW[0:256] + V2[bc]·HW[256:512] + Hb
// ---------------------------------------------------------------------------
__global__ __launch_bounds__(256) void final_kernel(
    const float* __restrict__ V1, const float* __restrict__ V2,
    const float* __restrict__ HW, const float* __restrict__ Hb,
    float* __restrict__ y)
{
  const int t = threadIdx.x;
  const int w = t >> 6, l = t & 63;
  const int bc = blockIdx.x * 4 + w;
  float4 v1 = *(const float4*)&V1[(size_t)bc * Dc + l * 4];
  float4 h1 = *(const float4*)&HW[l * 4];
  float4 v2 = *(const float4*)&V2[(size_t)bc * Dc + l * 4];
  float4 h2 = *(const float4*)&HW[Dc + l * 4];
  float sum = v1.x * h1.x + v1.y * h1.y + v1.z * h1.z + v1.w * h1.w
            + v2.x * h2.x + v2.y * h2.y + v2.z * h2.z + v2.w * h2.w;
#pragma unroll
  for (int off = 32; off > 0; off >>= 1) sum += __shfl_down(sum, off);
  if (l == 0) y[bc] = sum + Hb[0];
}

extern "C" void kernel_launch(void* const* d_in, const int* in_sizes, int n_in,
                              void* d_out, int out_size, void* d_ws, size_t ws_size,
                              hipStream_t stream) {
  (void)in_sizes; (void)n_in; (void)out_size; (void)ws_size;
  const int*   inp  = (const int*)d_in[0];
  const int*   cand = (const int*)d_in[1];
  const float* EmbA = (const float*)d_in[4];
  const float* EmbB = (const float*)d_in[5];
  const float* FW   = (const float*)d_in[6];
  const float* Fb   = (const float*)d_in[7];
  const float* GW   = (const float*)d_in[8];
  const float* Gb   = (const float*)d_in[9];
  const float* HW   = (const float*)d_in[10];
  const float* Hb   = (const float*)d_in[11];
  float* y = (float*)d_out;

  const size_t nA = (size_t)Bc * Sc * Dc;   // 1,048,576 elems
  const size_t nB = (size_t)VOc * Dc;       // 1,280,000 elems
  const size_t nV = (size_t)Bc * Cc * Dc;   //   524,288 elems
  const size_t nW = (size_t)768 * 256;      //   196,608 elems
  char* ws = (char*)d_ws;
  unsigned short* Am_hi = (unsigned short*)ws;              ws += nA * 2;
  unsigned short* Am_lo = (unsigned short*)ws;              ws += nA * 2;
  unsigned short* FB_hi = (unsigned short*)ws;              ws += nB * 2;
  unsigned short* FB_lo = (unsigned short*)ws;              ws += nB * 2;
  unsigned short* UaT_hi = (unsigned short*)ws;             ws += nA * 2;
  unsigned short* UaT_lo = (unsigned short*)ws;             ws += nA * 2;
  unsigned*       Ub_hl  = (unsigned*)ws;                   ws += nB * 4;
  float*          Ta     = (float*)ws;                      ws += nA * 4;
  float*          Tb     = (float*)ws;                      ws += nB * 4;
  float*          V1     = (float*)ws;                      ws += nV * 4;
  float*          V2     = (float*)ws;                      ws += nV * 4;
  unsigned short* WT_hi  = (unsigned short*)ws;             ws += nW * 2;
  unsigned short* WT_lo  = (unsigned short*)ws;             // total ~33.4 MB

  hipFuncSetAttribute((const void*)fused_kernel,
                      hipFuncAttributeMaxDynamicSharedMemorySize, SMEM_BYTES);

  prep_kernel<<<768, 256, 0, stream>>>(FW, GW, WT_hi, WT_lo);
  transform_kernel<<<dim3(143, 6), 256, 0, stream>>>(
      EmbA, inp, EmbB, WT_hi, WT_lo, Fb, Gb,
      Am_hi, Am_lo, Ta, UaT_hi, UaT_lo, FB_hi, FB_lo, Tb, Ub_hl);
  fused_kernel<<<Bc * Cc, 512, SMEM_BYTES, stream>>>(
      cand, Am_hi, Am_lo, FB_hi, FB_lo, UaT_hi, UaT_lo, Ub_hl, Ta, Tb, V1, V2);
  final_kernel<<<(Bc * Cc) / 4, 256, 0, stream>>>(V1, V2, HW, Hb, y);
}